// Round 19
// baseline (323.509 us; speedup 1.0000x reference)
//
#include <hip/hip_runtime.h>
#include <math.h>

// Problem constants
#define Bn 16
#define Ln 1024
#define Dn 768
#define Hn 12
#define PHDn 64
#define NK 33                 // Hermitian bins for 64-pt DFT (k=0..32)
#define NHK (Hn * NK)         // 396
#define TWOPI_64 0.09817477042468103f   // 2*pi/64

typedef short s16x8 __attribute__((ext_vector_type(8)));
typedef float f32x4 __attribute__((ext_vector_type(4)));
typedef unsigned short u16x4 __attribute__((ext_vector_type(4)));

__device__ __forceinline__ unsigned short f2bf(float f) {
    unsigned int u = __float_as_uint(f);
    unsigned int r = (u + 0x7FFFu + ((u >> 16) & 1u)) >> 16;
    return (unsigned short)r;
}
__device__ __forceinline__ float bf2f(unsigned short s) {
    unsigned int u = ((unsigned int)s) << 16;
    return __uint_as_float(u);
}
__device__ __forceinline__ float2 cmul(float2 a, float2 b) {
    return make_float2(a.x * b.x - a.y * b.y, a.x * b.y + a.y * b.x);
}
__device__ __forceinline__ float2 cadd(float2 a, float2 b) { return make_float2(a.x + b.x, a.y + b.y); }
__device__ __forceinline__ float2 csub(float2 a, float2 b) { return make_float2(a.x - b.x, a.y - b.y); }
__device__ __forceinline__ unsigned int packbf(float re, float im) {
    return (unsigned int)f2bf(re) | ((unsigned int)f2bf(im) << 16);
}
__device__ __forceinline__ float2 unpackbf(unsigned int v) {
    return make_float2(bf2f((unsigned short)(v & 0xffff)), bf2f((unsigned short)(v >> 16)));
}

// LDS bank swizzle for the radix-2 tap FFT (involution)
#define SW(j) ((j) ^ (((j) >> 2) & 12) ^ (((j) >> 6) & 3))
// Padded index for the radix-8 conv FFT buffer
#define PD(j) ((j) + ((j) >> 4))

// ---------------- workspace layout (float offsets) ----------------
static const size_t O_P    = 0;          // psf taps; later SP_bf
static const size_t O_PSFH = 786432;     // psf-hat; later pre_w_bf + post_w_bf
static const size_t O_PART = 1376256;    // sn column-sum partials
static const size_t O_QH   = 1597440;    // q-hat
static const size_t O_X    = 1598240;    // x_bf [0,6291456) + Wf1 + Wi1
static const size_t O_XT   = 7897888;    // xT_bf [pre_proj -> sparse]
static const size_t O_XH   = 14189344;   // XHb u32 [dft -> conv]; CE_bf at +6488064
static const size_t O_YH   = 27157280;   // emb_bf [cvt -> ln]; YHb u32 at +6291456
static const size_t O_SPE  = 40146080;   // phf early; spe_bf later; G_bf at +3145728
static const size_t O_V    = 52728992;
static const size_t O_UR   = 52730016;
static const size_t O_SIG  = 52731040;   // inv_sigma + q[768] after

// ---------------- psf softmax over 2047 taps (1023 are zeros) ----------------
__global__ __launch_bounds__(256) void k_psf_softmax(const float* __restrict__ psfs,
                                                     float* __restrict__ p,
                                                     float* __restrict__ q) {
    int he = blockIdx.x;            // h*64+e
    int h = he >> 6, e = he & 63;
    int tid = threadIdx.x;
    float ev[4];
    float s = 0.f;
#pragma unroll
    for (int i = 0; i < 4; ++i) {
        int t = tid + 256 * i;
        float v = psfs[((size_t)h * 2047 + t) * 64 + e];
        ev[i] = expf(v);
        s += ev[i];
    }
    __shared__ float red[256];
    red[tid] = s; __syncthreads();
    for (int st = 128; st > 0; st >>= 1) {
        if (tid < st) red[tid] += red[tid + st];
        __syncthreads();
    }
    float denom = red[0] + 1023.0f;
    float inv = 1.0f / denom;
#pragma unroll
    for (int i = 0; i < 4; ++i) {
        int t = tid + 256 * i;
        p[((size_t)h * 1024 + t) * 64 + e] = ev[i] * inv;
    }
    if (tid == 0) q[he] = inv;
}

// ---------------- DFT over head-dim of psf taps (4 t per block) ----------------
__global__ __launch_bounds__(256) void k_psf_dft(const float* __restrict__ p,
                                                 float* __restrict__ psfh) {
    int blk = blockIdx.x;           // h*256 + tb
    int h = blk >> 8, tb = blk & 255;
    int t0 = tb * 4;
    int tid = threadIdx.x;
    int w = tid >> 6, lane = tid & 63;
    __shared__ float pv[4][64], cc[64], ssn[64];
    if (tid < 64) {
        float ang = TWOPI_64 * tid;
        cc[tid] = cosf(ang); ssn[tid] = sinf(ang);
    }
    pv[w][lane] = p[((size_t)h * 1024 + t0 + w) * 64 + lane];
    __syncthreads();
    if (lane < NK) {
        float re = 0.f, im = 0.f;
#pragma unroll 8
        for (int e = 0; e < 64; ++e) {
            int j = (lane * e) & 63;
            float v = pv[w][e];
            re += v * cc[j];
            im -= v * ssn[j];
        }
        size_t o = (((size_t)h * NK + lane) * 1024 + t0 + w) * 2;
        psfh[o] = re; psfh[o + 1] = im;
    }
}

// ---------------- DFT of uniform tap value q[h][e] ----------------
__global__ __launch_bounds__(64) void k_q_dft(const float* __restrict__ q,
                                              float* __restrict__ qh) {
    int h = blockIdx.x;
    int tid = threadIdx.x;
    __shared__ float qv[64], cc[64], ssn[64];
    qv[tid] = q[h * 64 + tid];
    float ang = TWOPI_64 * tid;
    cc[tid] = cosf(ang); ssn[tid] = sinf(ang);
    __syncthreads();
    if (tid < NK) {
        float re = 0.f, im = 0.f;
        for (int e = 0; e < 64; ++e) {
            int j = (tid * e) & 63;
            re += qv[e] * cc[j];
            im -= qv[e] * ssn[j];
        }
        qh[(h * NK + tid) * 2] = re;
        qh[(h * NK + tid) * 2 + 1] = im;
    }
}

// 512-entry tw table for the tap FFT (w2 computed as w1^2)
__device__ __forceinline__ void build_tw512(float2* tw, int tid) {
#pragma unroll
    for (int it = 0; it < 2; ++it) {
        int j = tid + it * 256;
        float a = (float)j * 3.0679615757712823e-3f;   // 2*pi/2048
        float sv, cv;
        __sincosf(a, &sv, &cv);
        tw[j] = make_float2(cv, -sv);
    }
}

// 1024-entry tw table for the conv FFT (direct w2/w4 lookups)
__device__ __forceinline__ void build_tw1024(float2* tw, int tid) {
#pragma unroll
    for (int it = 0; it < 4; ++it) {
        int j = tid + it * 256;
        float a = (float)j * 3.0679615757712823e-3f;   // 2*pi/2048
        float sv, cv;
        __sincosf(a, &sv, &cv);
        tw[j] = make_float2(cv, -sv);
    }
}

// ---------------- fused radix-2 stage-pair (swizzled LDS, w2 = w1^2) — tap FFT ----------------
__device__ __forceinline__ void fft_pair(const float2* __restrict__ X,
                                         float2* __restrict__ Y,
                                         const float2* __restrict__ tw,
                                         int tid, int m) {
#pragma unroll
    for (int it = 0; it < 2; ++it) {
        int i = tid + it * 256;
        int r = i & (m - 1);
        int am = i - r;
        float2 w1 = tw[am];
        float2 w1b = make_float2(w1.y, -w1.x);
        float2 w2 = cmul(w1, w1);
        float2 x0 = X[SW(i)], x1 = X[SW(i + 512)], x2 = X[SW(i + 1024)], x3 = X[SW(i + 1536)];
        float2 y0 = cadd(x0, x2);
        float2 y1 = cmul(csub(x0, x2), w1);
        float2 y2 = cadd(x1, x3);
        float2 y3 = cmul(csub(x1, x3), w1b);
        int o = 4 * am + r;
        Y[SW(o)] = cadd(y0, y2);
        Y[SW(o + m)] = cadd(y1, y3);
        Y[SW(o + 2 * m)] = cmul(csub(y0, y2), w2);
        Y[SW(o + 3 * m)] = cmul(csub(y1, y3), w2);
    }
}

// ---------------- FFT of tap vector per (h,k) (radix-2 pairs) ----------------
__global__ __launch_bounds__(256) void k_tap_fft(const float* __restrict__ psfh,
                                                 const float* __restrict__ qh,
                                                 float* __restrict__ phf) {
    __shared__ float2 A[2048], B[2048], tw[512];
    int hk = blockIdx.x, tid = threadIdx.x;
    build_tw512(tw, tid);
    float2 qv = make_float2(qh[hk * 2], qh[hk * 2 + 1]);
    const float2* Pg = (const float2*)(psfh + (size_t)hk * 2048);
    __syncthreads();
#pragma unroll
    for (int it = 0; it < 2; ++it) {
        int i = tid + it * 256;
        float2 x0 = Pg[i], x1 = Pg[i + 512];
        float2 x2 = (i == 0) ? make_float2(0.f, 0.f) : qv;
        float2 x3 = qv;
        float2 w1 = tw[i];
        float2 w1b = make_float2(w1.y, -w1.x);
        float2 w2 = cmul(w1, w1);
        float2 y0 = cadd(x0, x2);
        float2 y1 = cmul(csub(x0, x2), w1);
        float2 y2 = cadd(x1, x3);
        float2 y3 = cmul(csub(x1, x3), w1b);
        int o = 4 * i;
        A[SW(o)] = cadd(y0, y2);
        A[SW(o + 1)] = cadd(y1, y3);
        A[SW(o + 2)] = cmul(csub(y0, y2), w2);
        A[SW(o + 3)] = cmul(csub(y1, y3), w2);
    }
    __syncthreads();
    fft_pair(A, B, tw, tid, 4);   __syncthreads();
    fft_pair(B, A, tw, tid, 16);  __syncthreads();
    fft_pair(A, B, tw, tid, 64);  __syncthreads();
    fft_pair(B, A, tw, tid, 256); __syncthreads();
    float2* out = (float2*)(phf + (size_t)hk * 4096);
#pragma unroll
    for (int it = 0; it < 4; ++it) {
        int t = tid + it * 256;
        float2 lo = A[SW(t)], hi = A[SW(t + 1024)];
        out[t] = cadd(lo, hi);
        out[t + 1024] = csub(lo, hi);
    }
}

// ---------------- radix-8 triple: three radix-2 Stockham stages in registers ----------------
__device__ __forceinline__ void triple_tail(float2 z0, float2 z1, float2 z2, float2 z3,
                                            float2 zz0, float2 zz1, float2 zz2, float2 zz3,
                                            float2 w2, float2 w4, float2* o) {
    float2 w2b = make_float2(w2.y, -w2.x);
    float2 a0 = cadd(z0, z2),   a2 = cmul(csub(z0, z2), w2);
    float2 b0 = cadd(z1, z3),   b2 = cmul(csub(z1, z3), w2b);
    float2 a1 = cadd(zz0, zz2), a3 = cmul(csub(zz0, zz2), w2);
    float2 b1 = cadd(zz1, zz3), b3 = cmul(csub(zz1, zz3), w2b);
    o[0] = cadd(a0, b0); o[4] = cmul(csub(a0, b0), w4);
    o[1] = cadd(a1, b1); o[5] = cmul(csub(a1, b1), w4);
    o[2] = cadd(a2, b2); o[6] = cmul(csub(a2, b2), w4);
    o[3] = cadd(a3, b3); o[7] = cmul(csub(a3, b3), w4);
}

// 1024-entry-table variant: all twiddles are direct lookups (am <= 255 -> 4am <= 1020)
__device__ __forceinline__ void fft_triple_lut(const float2* x, const float2* __restrict__ tw,
                                               int am, float2* o) {
    float2 w10 = tw[am], w11 = tw[am + 256];
    float2 w2 = tw[2 * am], w4 = tw[4 * am];
    float2 w10b = make_float2(w10.y, -w10.x), w11b = make_float2(w11.y, -w11.x);
    float2 z0 = cadd(x[0], x[4]), z1 = cadd(x[1], x[5]);
    float2 z2 = cadd(x[2], x[6]), z3 = cadd(x[3], x[7]);
    float2 zz0 = cmul(csub(x[0], x[4]), w10);
    float2 zz1 = cmul(csub(x[1], x[5]), w11);
    float2 zz2 = cmul(csub(x[2], x[6]), w10b);
    float2 zz3 = cmul(csub(x[3], x[7]), w11b);
    triple_tail(z0, z1, z2, z3, zz0, zz1, zz2, zz3, w2, w4, o);
}

// ---------------- per-(b,h,k) conv via circular-2048 FFT — radix-8, 1024-entry tw ----------------
__global__ __launch_bounds__(256) void k_conv_fft(const unsigned int* __restrict__ XHb,
                                                  const float* __restrict__ PHF,
                                                  unsigned int* __restrict__ YHb) {
    __shared__ float2 S[2176], tw[1024];
    int bhk = blockIdx.x, tid = threadIdx.x;
    int hk = bhk % NHK;
    build_tw1024(tw, tid);
    const unsigned int* Xg = XHb + (size_t)bhk * 1024;
    float2 x[8], o[8];
#pragma unroll
    for (int k = 0; k < 4; ++k) x[k] = unpackbf(Xg[tid + 256 * k]);
    __syncthreads();                              // tw ready
    {
        float2 w10 = tw[tid], w11 = tw[tid + 256];
        float2 w2 = tw[2 * tid], w4 = tw[4 * tid];
        float2 w10b = make_float2(w10.y, -w10.x), w11b = make_float2(w11.y, -w11.x);
        float2 zz0 = cmul(x[0], w10), zz1 = cmul(x[1], w11);
        float2 zz2 = cmul(x[2], w10b), zz3 = cmul(x[3], w11b);
        triple_tail(x[0], x[1], x[2], x[3], zz0, zz1, zz2, zz3, w2, w4, o);
    }
#pragma unroll
    for (int k = 0; k < 8; ++k) S[PD(8 * tid + k)] = o[k];
    __syncthreads();
    {
        int r = tid & 7, am = tid - r;
#pragma unroll
        for (int k = 0; k < 8; ++k) x[k] = S[PD(tid + 256 * k)];
        __syncthreads();
        fft_triple_lut(x, tw, am, o);
        int base = 8 * am + r;
#pragma unroll
        for (int k = 0; k < 8; ++k) S[PD(base + 8 * k)] = o[k];
    }
    __syncthreads();
    {
        int r = tid & 63, am = tid - r;
#pragma unroll
        for (int k = 0; k < 8; ++k) x[k] = S[PD(tid + 256 * k)];
        __syncthreads();
        fft_triple_lut(x, tw, am, o);
        int base = 8 * am + r;
#pragma unroll
        for (int k = 0; k < 8; ++k) S[PD(base + 64 * k)] = o[k];
    }
    __syncthreads();
    const float2* P = (const float2*)(PHF + (size_t)hk * 4096);
    float2 v[8];
#pragma unroll
    for (int it = 0; it < 2; ++it) {
        int i2 = tid + 256 * it;
        float2 g0 = S[PD(i2)], g1 = S[PD(i2 + 512)], g2 = S[PD(i2 + 1024)], g3 = S[PD(i2 + 1536)];
        float2 y0 = cadd(g0, g2), y1 = csub(g0, g2);
        float2 y2 = cadd(g1, g3);
        float2 d13 = csub(g1, g3);
        float2 y3 = make_float2(d13.y, -d13.x);
        float2 F0 = cadd(y0, y2);
        float2 F1 = cadd(y1, y3);
        float2 F2 = csub(y0, y2);
        float2 F3 = csub(y1, y3);
        float2 V0 = cmul(F0, P[i2]);
        float2 V1 = cmul(F1, P[i2 + 512]);
        float2 V2 = cmul(F2, P[i2 + 1024]);
        float2 V3 = cmul(F3, P[i2 + 1536]);
        v[it]     = make_float2(V0.x, -V0.y);
        v[it + 2] = make_float2(V1.x, -V1.y);
        v[it + 4] = make_float2(V2.x, -V2.y);
        v[it + 6] = make_float2(V3.x, -V3.y);
    }
    __syncthreads();
    fft_triple_lut(v, tw, tid, o);
#pragma unroll
    for (int k = 0; k < 8; ++k) S[PD(8 * tid + k)] = o[k];
    __syncthreads();
    {
        int r = tid & 7, am = tid - r;
#pragma unroll
        for (int k = 0; k < 8; ++k) x[k] = S[PD(tid + 256 * k)];
        __syncthreads();
        fft_triple_lut(x, tw, am, o);
        int base = 8 * am + r;
#pragma unroll
        for (int k = 0; k < 8; ++k) S[PD(base + 8 * k)] = o[k];
    }
    __syncthreads();
    {
        int r = tid & 63, am = tid - r;
#pragma unroll
        for (int k = 0; k < 8; ++k) x[k] = S[PD(tid + 256 * k)];
        __syncthreads();
        fft_triple_lut(x, tw, am, o);
        int base = 8 * am + r;
#pragma unroll
        for (int k = 0; k < 8; ++k) S[PD(base + 64 * k)] = o[k];
    }
    __syncthreads();
    unsigned int* Yg = YHb + (size_t)bhk * 1024;
    const float inv_n = 1.0f / 2048.0f;
#pragma unroll
    for (int it = 0; it < 2; ++it) {
        int i2 = tid + 256 * it;
        float2 g0 = S[PD(i2)], g1 = S[PD(i2 + 512)], g2 = S[PD(i2 + 1024)], g3 = S[PD(i2 + 1536)];
        float2 s02 = cadd(g0, g2), d02 = csub(g0, g2);
        float2 s13 = cadd(g1, g3);
        float2 d13 = csub(g1, g3);
        float2 mj13 = make_float2(d13.y, -d13.x);
        float2 o0 = cadd(s02, s13);
        float2 o1 = cadd(d02, mj13);
        Yg[i2] = packbf(o0.x * inv_n, -o0.y * inv_n);
        Yg[i2 + 512] = packbf(o1.x * inv_n, -o1.y * inv_n);
    }
}

// ---------------- build both per-head DFT blocks ----------------
__global__ __launch_bounds__(64) void k_build_w(unsigned short* __restrict__ Wf,
                                                unsigned short* __restrict__ Wi) {
    int m = blockIdx.x;                  // 0..255
    int c = threadIdx.x;                 // 0..63
    if (m < 128) {
        float val = 0.f;
        if (m < 66) {
            int k = m >> 1, od = m & 1;
            int j = (k * c) & 63;
            float ang = TWOPI_64 * (float)j;
            val = od ? -sinf(ang) : cosf(ang);
        }
        Wf[m * 64 + c] = f2bf(val);
    } else {
        int mm = m - 128;
        float val = 0.f;
        if (mm < 64) {
            int d = mm;
            int k, od;
            float ck;
            if (c == 0)      { k = 0;  od = 0; ck = 1.f / 64.f; }
            else if (c == 1) { k = 32; od = 0; ck = 1.f / 64.f; }
            else             { k = c >> 1; od = c & 1; ck = 2.f / 64.f; }
            int j = (k * d) & 63;
            float ang = TWOPI_64 * (float)j;
            val = od ? -sinf(ang) * ck : cosf(ang) * ck;
        }
        Wi[mm * 64 + c] = f2bf(val);
    }
}

// ---------------- BK=64 MFMA core (bf16 sources, 256 threads) ----------------
__device__ __forceinline__ void mfma_core64(const unsigned short* __restrict__ gA0,
                                            const unsigned short* __restrict__ gB0,
                                            int nkt,
                                            unsigned short* __restrict__ As,
                                            unsigned short* __restrict__ Bs,
                                            int tid, int lane, int wr, int wc,
                                            f32x4 acc[4][4]) {
    int r0 = tid >> 1, hs = (tid & 1) << 2;
    int wbase = r0 * 64;
    int swr = r0 & 7;
    int kg = lane >> 4, cl = lane & 15;
    int fra[8], frb[8];
#pragma unroll
    for (int kk = 0; kk < 2; ++kk)
#pragma unroll
        for (int i = 0; i < 4; ++i) {
            int ra = wr * 64 + i * 16 + cl;
            fra[kk * 4 + i] = ra * 64 + (((kk * 4 + kg) ^ (ra & 7)) << 3);
            int rb = wc * 64 + i * 16 + cl;
            frb[kk * 4 + i] = rb * 64 + (((kk * 4 + kg) ^ (rb & 7)) << 3);
        }
    s16x8 a[4], b[4];
#pragma unroll
    for (int l = 0; l < 4; ++l) {
        a[l] = *(const s16x8*)(gA0 + l * 8);
        b[l] = *(const s16x8*)(gB0 + l * 8);
    }
    for (int kt = 0; kt < nkt; ++kt) {
        __syncthreads();
#pragma unroll
        for (int l = 0; l < 4; ++l) {
            *(s16x8*)&As[wbase + (((hs + l) ^ swr) << 3)] = a[l];
            *(s16x8*)&Bs[wbase + (((hs + l) ^ swr) << 3)] = b[l];
        }
        __syncthreads();
        if (kt + 1 < nkt) {
            size_t ko = (size_t)(kt + 1) * 64;
#pragma unroll
            for (int l = 0; l < 4; ++l) {
                a[l] = *(const s16x8*)(gA0 + ko + l * 8);
                b[l] = *(const s16x8*)(gB0 + ko + l * 8);
            }
        }
#pragma unroll
        for (int kk = 0; kk < 2; ++kk) {
            s16x8 af[4], bfr[4];
#pragma unroll
            for (int i = 0; i < 4; ++i) af[i] = *(const s16x8*)&As[fra[kk * 4 + i]];
#pragma unroll
            for (int i = 0; i < 4; ++i) bfr[i] = *(const s16x8*)&Bs[frb[kk * 4 + i]];
#pragma unroll
            for (int mi = 0; mi < 4; ++mi)
#pragma unroll
                for (int ni = 0; ni < 4; ++ni)
                    acc[mi][ni] = __builtin_amdgcn_mfma_f32_16x16x32_bf16(af[mi], bfr[ni], acc[mi][ni], 0, 0, 0);
        }
    }
}

// ---------------- projection GEMM: BM=64,BN=256,BK=128, 512 threads (8 waves 2x4) ----------------
// 6 k-iterations (half the barriers); LDS-staged coalesced epilogue; optional fused xT.
__global__ __launch_bounds__(512) void k_mfma_proj(const unsigned short* __restrict__ A,
                                                   const unsigned short* __restrict__ W,
                                                   const float* __restrict__ bias,
                                                   unsigned short* __restrict__ C,
                                                   unsigned short* __restrict__ XT) {
    const int K = Dn, N = Dn;
    int n0 = blockIdx.x * 256, m0 = blockIdx.y * 64;
    int tid = threadIdx.x;
    int lane = tid & 63, wave = tid >> 6;    // 0..7
    int wr = wave >> 2, wc = wave & 3;       // 2 x 4 (wave tile: 32m x 64n)
    __shared__ __align__(16) unsigned short LDSu[40960];   // A[0..8191] + B[8192..40959]
    unsigned short* As = LDSu;
    unsigned short* Bs = LDSu + 8192;
    f32x4 acc[2][4] = {};
    int ra0 = tid >> 3, sa0 = (tid & 7) * 2;  // A: 64 rows x 16 slots, 2 slots/thread
    int rb0 = tid >> 1, sb0 = (tid & 1) * 8;  // B: 256 rows x 16 slots, 8 slots/thread
    const unsigned short* gA = A + (size_t)(m0 + ra0) * K + sa0 * 8;
    const unsigned short* gB = W + (size_t)(n0 + rb0) * K + sb0 * 8;
    int kg = lane >> 4, cl = lane & 15;
    int fra[8], frb[16];
#pragma unroll
    for (int kk = 0; kk < 4; ++kk) {
#pragma unroll
        for (int i = 0; i < 2; ++i) {
            int ra = wr * 32 + i * 16 + cl;
            fra[kk * 2 + i] = ra * 128 + (((kk * 4 + kg) ^ (ra & 15)) << 3);
        }
#pragma unroll
        for (int i = 0; i < 4; ++i) {
            int rb = wc * 64 + i * 16 + cl;
            frb[kk * 4 + i] = rb * 128 + (((kk * 4 + kg) ^ (rb & 15)) << 3);
        }
    }
    s16x8 a[2], b[8];
#pragma unroll
    for (int l = 0; l < 2; ++l) a[l] = *(const s16x8*)(gA + l * 8);
#pragma unroll
    for (int l = 0; l < 8; ++l) b[l] = *(const s16x8*)(gB + l * 8);
    const int nkt = K >> 7;   // 6
    for (int kt = 0; kt < nkt; ++kt) {
        __syncthreads();
#pragma unroll
        for (int l = 0; l < 2; ++l)
            *(s16x8*)&As[ra0 * 128 + (((sa0 + l) ^ (ra0 & 15)) << 3)] = a[l];
#pragma unroll
        for (int l = 0; l < 8; ++l)
            *(s16x8*)&Bs[rb0 * 128 + (((sb0 + l) ^ (rb0 & 15)) << 3)] = b[l];
        __syncthreads();
        if (kt + 1 < nkt) {
            size_t ko = (size_t)(kt + 1) * 128;
#pragma unroll
            for (int l = 0; l < 2; ++l) a[l] = *(const s16x8*)(gA + ko + l * 8);
#pragma unroll
            for (int l = 0; l < 8; ++l) b[l] = *(const s16x8*)(gB + ko + l * 8);
        }
#pragma unroll
        for (int kk = 0; kk < 4; ++kk) {
            s16x8 af[2], bfr[4];
#pragma unroll
            for (int i = 0; i < 2; ++i) af[i] = *(const s16x8*)&As[fra[kk * 2 + i]];
#pragma unroll
            for (int i = 0; i < 4; ++i) bfr[i] = *(const s16x8*)&Bs[frb[kk * 4 + i]];
#pragma unroll
            for (int mi = 0; mi < 2; ++mi)
#pragma unroll
                for (int ni = 0; ni < 4; ++ni)
                    acc[mi][ni] = __builtin_amdgcn_mfma_f32_16x16x32_bf16(af[mi], bfr[ni], acc[mi][ni], 0, 0, 0);
        }
    }
    // ---- LDS-staged coalesced epilogue ----
    __syncthreads();                          // all MFMA LDS reads done; overlay staging
    unsigned short* ST = LDSu + wave * 2304;  // per-wave 32 rows x 72 (pad; 16B-aligned)
#pragma unroll
    for (int ni = 0; ni < 4; ++ni) {
        int gn = n0 + wc * 64 + ni * 16 + cl;
        float bv = bias[gn];
#pragma unroll
        for (int mi = 0; mi < 2; ++mi) {
            f32x4 v = acc[mi][ni];
#pragma unroll
            for (int ri = 0; ri < 4; ++ri)
                ST[(mi * 16 + kg * 4 + ri) * 72 + ni * 16 + cl] = f2bf(v[ri] + bv);
        }
    }
    __syncthreads();
    // C rows: lane pair covers one row (128B contiguous per 2 lanes)
    {
        int r = lane >> 1, ch = (lane & 1) * 32;
        int gm = m0 + wr * 32 + r;
        const unsigned short* src = ST + r * 72 + ch;
        unsigned short* dst = C + (size_t)gm * N + n0 + wc * 64 + ch;
#pragma unroll
        for (int j = 0; j < 4; ++j)
            *(s16x8*)(dst + j * 8) = *(const s16x8*)(src + j * 8);
    }
    // xT emission (pre-projection): lane reads one column of staged tile
    if (XT) {
        int gn = n0 + wc * 64 + lane;
        unsigned short tmp[32];
#pragma unroll
        for (int r = 0; r < 32; ++r) tmp[r] = ST[r * 72 + lane];
        int b0 = m0 >> 10;
        int t0 = (m0 & 1023) + wr * 32;
        unsigned short* dst = XT + ((size_t)b0 * Dn + gn) * Ln + t0;
#pragma unroll
        for (int j = 0; j < 4; ++j)
            *(s16x8*)(dst + j * 8) = *(const s16x8*)&tmp[j * 8];
    }
}

// ---------------- per-head forward DFT GEMM -> bf16 complex planes ----------------
__global__ __launch_bounds__(256) void k_mfma_dft_h(const unsigned short* __restrict__ Wf1,
                                                    const unsigned short* __restrict__ Xb,
                                                    unsigned int* __restrict__ XHb) {
    int n0 = blockIdx.x * 128;          // x-row tile
    int h = blockIdx.y;                 // head
    int tid = threadIdx.x;
    int lane = tid & 63, wave = tid >> 6;
    int wr = wave >> 1, wc = wave & 1;
    __shared__ __align__(16) unsigned short As[8192], Bs[8192];
    f32x4 acc[4][4] = {};
    int r0 = tid >> 1, hs = (tid & 1) << 2;
    const unsigned short* gA0 = Wf1 + r0 * 64 + hs * 8;
    const unsigned short* gB0 = Xb + (size_t)(n0 + r0) * Dn + h * 64 + hs * 8;
    mfma_core64(gA0, gB0, 1, As, Bs, tid, lane, wr, wc, acc);
    int kg = lane >> 4, cl = lane & 15;
#pragma unroll
    for (int ni = 0; ni < 4; ++ni) {
        int gn = n0 + wc * 64 + ni * 16 + cl;   // global x row
        int b = gn >> 10, u = gn & 1023;
#pragma unroll
        for (int mi = 0; mi < 4; ++mi) {
            int gmb = wr * 64 + mi * 16 + kg * 4;
            f32x4 v = acc[mi][ni];
#pragma unroll
            for (int rp = 0; rp < 2; ++rp) {
                int m = gmb + rp * 2;           // even: pair (re,im) of bin m>>1
                if (m < 66) {
                    size_t plane = (size_t)(b * Hn + h) * NK + (m >> 1);
                    XHb[plane * 1024 + u] = packbf(v[rp * 2], v[rp * 2 + 1]);
                }
            }
        }
    }
}

// ---------------- per-head inverse DFT + GELU GEMM (fused YHb transpose staging) ----------------
__global__ __launch_bounds__(256) void k_mfma_idft_h(const unsigned int* __restrict__ YHb,
                                                     const unsigned short* __restrict__ Wi1,
                                                     unsigned short* __restrict__ G) {
    int m0 = blockIdx.x * 128;          // global row tile (b*1024+u0)
    int h = blockIdx.y;                 // head
    int b = m0 >> 10, u0 = m0 & 1023;
    int tid = threadIdx.x;
    int lane = tid & 63, wave = tid >> 6;
    int wr = wave >> 1, wc = wave & 1;
    __shared__ __align__(16) unsigned short As[8192], Bs[8192];
    int planeBase = (b * Hn + h) * NK;
#pragma unroll
    for (int i = 0; i < 17; ++i) {
        int idx = tid + i * 256;        // 33 k-planes x 128 rows
        if (idx < 4224) {
            int k = idx >> 7, uo = idx & 127;
            unsigned int v = YHb[(size_t)(planeBase + k) * 1024 + u0 + uo];
            unsigned short lo = (unsigned short)(v & 0xffff);
            unsigned short hi = (unsigned short)(v >> 16);
            int sw = uo & 7;
            int rb = uo * 64;
            if (k == 0) {
                As[rb + (sw << 3) + 0] = lo;
            } else if (k == 32) {
                As[rb + (sw << 3) + 1] = lo;
            } else {
                int c0 = 2 * k, c1 = 2 * k + 1;
                As[rb + (((c0 >> 3) ^ sw) << 3) + (c0 & 7)] = lo;
                As[rb + (((c1 >> 3) ^ sw) << 3) + (c1 & 7)] = hi;
            }
        }
    }
    {
        int r0 = tid >> 1, hs = (tid & 1) << 2;
        int swr = r0 & 7;
        const unsigned short* gB0 = Wi1 + r0 * 64 + hs * 8;
#pragma unroll
        for (int l = 0; l < 4; ++l)
            *(s16x8*)&Bs[r0 * 64 + (((hs + l) ^ swr) << 3)] = *(const s16x8*)(gB0 + l * 8);
    }
    __syncthreads();
    f32x4 acc[4][4] = {};
    int kg = lane >> 4, cl = lane & 15;
#pragma unroll
    for (int kk = 0; kk < 2; ++kk) {
        s16x8 af[4], bfr[4];
#pragma unroll
        for (int i = 0; i < 4; ++i) {
            int ra = wr * 64 + i * 16 + cl;
            af[i] = *(const s16x8*)&As[ra * 64 + (((kk * 4 + kg) ^ (ra & 7)) << 3)];
            int rbw = wc * 64 + i * 16 + cl;
            bfr[i] = *(const s16x8*)&Bs[rbw * 64 + (((kk * 4 + kg) ^ (rbw & 7)) << 3)];
        }
#pragma unroll
        for (int mi = 0; mi < 4; ++mi)
#pragma unroll
            for (int ni = 0; ni < 4; ++ni)
                acc[mi][ni] = __builtin_amdgcn_mfma_f32_16x16x32_bf16(af[mi], bfr[ni], acc[mi][ni], 0, 0, 0);
    }
#pragma unroll
    for (int ni = 0; ni < 4; ++ni) {
        int gn = wc * 64 + ni * 16 + cl;    // d index (valid < 64)
        if (gn < 64) {
#pragma unroll
            for (int mi = 0; mi < 4; ++mi) {
                int gm = m0 + wr * 64 + mi * 16 + kg * 4;
                f32x4 v = acc[mi][ni];
#pragma unroll
                for (int ri = 0; ri < 4; ++ri) {
                    float c = v[ri];
                    float g = c * 0.5f * (1.0f + erff(c * 0.70710678118f));
                    G[(size_t)(gm + ri) * Dn + h * 64 + gn] = f2bf(g);
                }
            }
        }
    }
}

// ---------------- sparse: spe_b = (tril(SP)/sigma) @ x_b — BM=128,BN=256, 512 threads ----------------
__global__ __launch_bounds__(512) void k_mfma_sparse(const unsigned short* __restrict__ SP,
                                                     const unsigned short* __restrict__ XT,
                                                     const float* __restrict__ sigbuf,
                                                     unsigned short* __restrict__ C) {
    int bx = blockIdx.x;
    int mt = bx & 7, nt = (bx >> 3) % 3, b = bx / 24;
    int m0 = mt * 128, n0 = nt * 256;
    const unsigned short* Xb = XT + (size_t)b * Dn * Ln;
    unsigned short* Cb = C + (size_t)b * Ln * Dn;
    int tid = threadIdx.x;
    int lane = tid & 63, wave = tid >> 6;
    int wr = wave >> 2, wc = wave & 3;       // 2 x 4
    __shared__ __align__(16) unsigned short As[8192], Bs[16384];
    f32x4 acc[4][4] = {};
    int ra0 = tid >> 2, sa0 = (tid & 3) * 2;
    int rb0 = tid >> 1, sb0 = (tid & 1) * 4;
    const unsigned short* gA = SP + (size_t)(m0 + ra0) * Ln + sa0 * 8;
    const unsigned short* gB = Xb + (size_t)(n0 + rb0) * Ln + sb0 * 8;
    int kg = lane >> 4, cl = lane & 15;
    int fra[8], frb[8];
#pragma unroll
    for (int kk = 0; kk < 2; ++kk)
#pragma unroll
        for (int i = 0; i < 4; ++i) {
            int ra = wr * 64 + i * 16 + cl;
            fra[kk * 4 + i] = ra * 64 + (((kk * 4 + kg) ^ (ra & 7)) << 3);
            int rb = wc * 64 + i * 16 + cl;
            frb[kk * 4 + i] = rb * 64 + (((kk * 4 + kg) ^ (rb & 7)) << 3);
        }
    s16x8 a[2], b2[4];
#pragma unroll
    for (int l = 0; l < 2; ++l) a[l] = *(const s16x8*)(gA + l * 8);
#pragma unroll
    for (int l = 0; l < 4; ++l) b2[l] = *(const s16x8*)(gB + l * 8);
    int nkt = 2 * mt + 2;            // only k-tiles with t0 <= m0+127 (tril)
    for (int kt = 0; kt < nkt; ++kt) {
        __syncthreads();
#pragma unroll
        for (int l = 0; l < 2; ++l)
            *(s16x8*)&As[ra0 * 64 + (((sa0 + l) ^ (ra0 & 7)) << 3)] = a[l];
#pragma unroll
        for (int l = 0; l < 4; ++l)
            *(s16x8*)&Bs[rb0 * 64 + (((sb0 + l) ^ (rb0 & 7)) << 3)] = b2[l];
        __syncthreads();
        if (kt + 1 < nkt) {
            size_t ko = (size_t)(kt + 1) * 64;
#pragma unroll
            for (int l = 0; l < 2; ++l) a[l] = *(const s16x8*)(gA + ko + l * 8);
#pragma unroll
            for (int l = 0; l < 4; ++l) b2[l] = *(const s16x8*)(gB + ko + l * 8);
        }
#pragma unroll
        for (int kk = 0; kk < 2; ++kk) {
            s16x8 af[4], bfr[4];
#pragma unroll
            for (int i = 0; i < 4; ++i) af[i] = *(const s16x8*)&As[fra[kk * 4 + i]];
#pragma unroll
            for (int i = 0; i < 4; ++i) bfr[i] = *(const s16x8*)&Bs[frb[kk * 4 + i]];
#pragma unroll
            for (int mi = 0; mi < 4; ++mi)
#pragma unroll
                for (int ni = 0; ni < 4; ++ni)
                    acc[mi][ni] = __builtin_amdgcn_mfma_f32_16x16x32_bf16(af[mi], bfr[ni], acc[mi][ni], 0, 0, 0);
        }
    }
    float invs = sigbuf[0];
#pragma unroll
    for (int ni = 0; ni < 4; ++ni) {
        int gn = n0 + wc * 64 + ni * 16 + cl;
#pragma unroll
        for (int mi = 0; mi < 4; ++mi) {
            int gm = m0 + wr * 64 + mi * 16 + kg * 4;
            f32x4 v = acc[mi][ni];
#pragma unroll
            for (int ri = 0; ri < 4; ++ri)
                Cb[(size_t)(gm + ri) * Dn + gn] = f2bf(v[ri] * invs);
        }
    }
}

// ---------------- conversions ----------------
__global__ __launch_bounds__(256) void k_cvt_bf16(const float* __restrict__ in,
                                                  unsigned short* __restrict__ out, int n4) {
    int i = blockIdx.x * 256 + threadIdx.x;
    if (i < n4) {
        float4 v = ((const float4*)in)[i];
        u16x4 o;
        o[0] = f2bf(v.x); o[1] = f2bf(v.y); o[2] = f2bf(v.z); o[3] = f2bf(v.w);
        *(u16x4*)&out[(size_t)i * 4] = o;
    }
}

// ---------------- fused: spectral-norm column partial sums + tril bf16 conversion ----------------
__global__ __launch_bounds__(256) void k_sn_prep(const float* __restrict__ Wm,
                                                 float* __restrict__ partial,
                                                 unsigned short* __restrict__ SPb) {
    int b = blockIdx.x;               // rows [16b, 16b+16)
    int tid = threadIdx.x;
    int c0 = tid * 4;
    float4 s = make_float4(0.f, 0.f, 0.f, 0.f);
#pragma unroll
    for (int i = 0; i < 16; ++i) {
        int row = b * 16 + i;
        float4 v = *(const float4*)&Wm[(size_t)row * 1024 + c0];
        s.x += v.x; s.y += v.y; s.z += v.z; s.w += v.w;
        u16x4 o;
        o[0] = (c0 + 0 <= row) ? f2bf(v.x) : 0;
        o[1] = (c0 + 1 <= row) ? f2bf(v.y) : 0;
        o[2] = (c0 + 2 <= row) ? f2bf(v.z) : 0;
        o[3] = (c0 + 3 <= row) ? f2bf(v.w) : 0;
        *(u16x4*)&SPb[(size_t)row * 1024 + c0] = o;
    }
    *(float4*)&partial[(size_t)b * 1024 + c0] = s;
}

__global__ __launch_bounds__(1024) void k_sn_v2(const float* __restrict__ partial,
                                                float* __restrict__ v) {
    int j = threadIdx.x;
    float s = 0.f;
#pragma unroll 8
    for (int i = 0; i < 64; ++i) s += partial[(size_t)i * 1024 + j];
    s *= 0.03125f;
    __shared__ float red[1024];
    red[j] = s * s; __syncthreads();
    for (int st = 512; st > 0; st >>= 1) {
        if (j < st) red[j] += red[j + st];
        __syncthreads();
    }
    float nrm = sqrtf(red[0]);
    v[j] = s / (nrm + 1e-12f);
}

__global__ __launch_bounds__(64) void k_sn_u(const float* __restrict__ Wm,
                                             const float* __restrict__ v,
                                             float* __restrict__ ur) {
    int i = blockIdx.x;
    int lane = threadIdx.x;
    float s = 0.f;
    for (int j = lane; j < 1024; j += 64) s += Wm[(size_t)i * 1024 + j] * v[j];
#pragma unroll
    for (int off = 32; off > 0; off >>= 1) s += __shfl_down(s, off);
    if (lane == 0) ur[i] = s;
}

__global__ __launch_bounds__(1024) void k_sn_sigma(const float* __restrict__ ur,
                                                   float* __restrict__ sig) {
    int i = threadIdx.x;
    __shared__ float red[1024];
    float u = ur[i];
    red[i] = u * u; __syncthreads();
    for (int st = 512; st > 0; st >>= 1) {
        if (i < st) red[i] += red[i + st];
        __syncthreads();
    }
    if (i == 0) {
        float ss = red[0];
        float sigma = ss / (sqrtf(ss) + 1e-12f);
        sig[0] = 1.0f / sigma;
    }
}

// ---------------- final residual + LayerNorm (all-bf16 inputs) ----------------
__global__ __launch_bounds__(256) void k_final_ln(const unsigned short* __restrict__ CE,
                                                  const unsigned short* __restrict__ SE,
                                                  const unsigned short* __restrict__ EMB,
                                                  const float* __restrict__ g,
                                                  const float* __restrict__ be,
                                                  float* __restrict__ out) {
    int r = blockIdx.x;
    int tid = threadIdx.x;
    float y[3];
    float s = 0.f;
#pragma unroll
    for (int i = 0; i < 3; ++i) {
        int o = tid + i * 256;
        size_t idx = (size_t)r * 768 + o;
        y[i] = bf2f(CE[idx]) + bf2f(SE[idx]) + bf2f(EMB[idx]);
        s += y[i];
    }
    __shared__ float red[256];
    red[tid] = s; __syncthreads();
    for (int st = 128; st > 0; st >>= 1) {
        if (tid < st) red[tid] += red[tid + st];
        __syncthreads();
    }
    float mu = red[0] * (1.f / 768.f);
    __syncthreads();
    float vs = 0.f;
#pragma unroll
    for (int i = 0; i < 3; ++i) { float d = y[i] - mu; vs += d * d; }
    red[tid] = vs; __syncthreads();
    for (int st = 128; st > 0; st >>= 1) {
        if (tid < st) red[tid] += red[tid + st];
        __syncthreads();
    }
    float var = red[0] * (1.f / 768.f);
    float rstd = rsqrtf(var + 1e-12f);
#pragma unroll
    for (int i = 0; i < 3; ++i) {
        int o = tid + i * 256;
        size_t idx = (size_t)r * 768 + o;
        out[idx] = (y[i] - mu) * rstd * g[o] + be[o];
    }
}

extern "C" void kernel_launch(void* const* d_in, const int* in_sizes, int n_in,
                              void* d_out, int out_size, void* d_ws, size_t ws_size,
                              hipStream_t stream) {
    const float* emb     = (const float*)d_in[0];
    const float* pre_w   = (const float*)d_in[1];
    const float* pre_b   = (const float*)d_in[2];
    const float* psfs    = (const float*)d_in[3];
    const float* post_w  = (const float*)d_in[4];
    const float* post_b  = (const float*)d_in[5];
    const float* spmat   = (const float*)d_in[6];
    const float* ln_g    = (const float*)d_in[7];
    const float* ln_b    = (const float*)d_in[8];
    float* out = (float*)d_out;
    float* ws = (float*)d_ws;

    float* p      = ws + O_P;
    float* psfh   = ws + O_PSFH;
    float* part   = ws + O_PART;
    float* qh     = ws + O_QH;
    float* q      = ws + O_SIG + 8;
    float* phf    = ws + O_SPE;                       // alias (dead after conv)
    float* v      = ws + O_V;
    float* urw    = ws + O_UR;
    float* sig    = ws + O_SIG;

    unsigned int* XHb = (unsigned int*)(ws + O_XH);                 // [dft -> conv]
    unsigned int* YHb = (unsigned int*)(ws + O_YH + 6291456);       // [conv -> idft]
    unsigned short* emb_bf    = (unsigned short*)(ws + O_YH);       // [cvt -> final_ln]
    unsigned short* x_bf      = (unsigned short*)(ws + O_X);
    unsigned short* Wf1       = (unsigned short*)(ws + O_X + 6291456);      // [128][64]
    unsigned short* Wi1       = (unsigned short*)(ws + O_X + 6295552);      // [128][64]
    unsigned short* xT_bf     = (unsigned short*)(ws + O_XT);               // [pre_proj -> sparse]
    unsigned short* CE_bf     = (unsigned short*)(ws + O_XH + 6488064);     // past XHb span
    unsigned short* spe_bf    = (unsigned short*)(ws + O_SPE);              // over dead phf
    unsigned short* G_bf      = (unsigned short*)(ws + O_SPE + 3145728);    // disjoint
    unsigned short* SP_bf     = (unsigned short*)(ws + O_P);                // over dead p
    unsigned short* pre_w_bf  = (unsigned short*)(ws + O_PSFH);             // over dead psfh
    unsigned short* post_w_bf = (unsigned short*)(ws + O_PSFH + 294912);

    // PSF preprocessing
    k_psf_softmax<<<Hn * 64, 256, 0, stream>>>(psfs, p, q);
    k_psf_dft<<<Hn * 256, 256, 0, stream>>>(p, psfh);
    k_q_dft<<<Hn, 64, 0, stream>>>(q, qh);
    k_tap_fft<<<NHK, 256, 0, stream>>>(psfh, qh, phf);

    // spectral norm scalar (fused colsum + SP tril bf16)
    k_sn_prep<<<64, 256, 0, stream>>>(spmat, part, SP_bf);
    k_sn_v2<<<1, 1024, 0, stream>>>(part, v);
    k_sn_u<<<1024, 64, 0, stream>>>(spmat, v, urw);
    k_sn_sigma<<<1, 1024, 0, stream>>>(urw, sig);

    // bf16 conversions + DFT block builds
    k_cvt_bf16<<<576, 256, 0, stream>>>(pre_w, pre_w_bf, 147456);
    k_cvt_bf16<<<576, 256, 0, stream>>>(post_w, post_w_bf, 147456);
    k_cvt_bf16<<<12288, 256, 0, stream>>>(emb, emb_bf, 3145728);
    k_build_w<<<256, 64, 0, stream>>>(Wf1, Wi1);

    // pre-projection (BM=64, BN=256, BK=128, coalesced epilogue) -> x bf16 + fused xT
    k_mfma_proj<<<dim3(3, 256), 512, 0, stream>>>(emb_bf, pre_w_bf, pre_b, x_bf, xT_bf);

    // head-dim DFT: per-head batched GEMM -> bf16 complex planes
    k_mfma_dft_h<<<dim3(128, Hn), 256, 0, stream>>>(Wf1, x_bf, XHb);

    // causal conv + uniform suffix via circular-2048 FFT (radix-8, 1024-entry tw LUT)
    k_conv_fft<<<Bn * NHK, 256, 0, stream>>>(XHb, phf, YHb);

    // inverse DFT + GELU: fused YHb transpose staging -> G bf16
    k_mfma_idft_h<<<dim3(128, Hn), 256, 0, stream>>>(YHb, Wi1, G_bf);

    // post-projection (BM=64, BN=256, BK=128, coalesced epilogue) -> CE bf16
    k_mfma_proj<<<dim3(3, 256), 512, 0, stream>>>(G_bf, post_w_bf, post_b, CE_bf, nullptr);

    // sparse branch (BN=256, triangular k-loop) -> spe bf16 (over dead phf)
    k_mfma_sparse<<<384, 512, 0, stream>>>(SP_bf, xT_bf, sig, spe_bf);

    // residual + LayerNorm (all-bf16 inputs)
    k_final_ln<<<Bn * Ln, 256, 0, stream>>>(CE_bf, spe_bf, emb_bf, ln_g, ln_b, out);
}

// Round 20
// 293.924 us; speedup vs baseline: 1.1007x; 1.1007x over previous
//
#include <hip/hip_runtime.h>
#include <math.h>

// Problem constants
#define Bn 16
#define Ln 1024
#define Dn 768
#define Hn 12
#define PHDn 64
#define NK 33                 // Hermitian bins for 64-pt DFT (k=0..32)
#define NHK (Hn * NK)         // 396
#define TWOPI_64 0.09817477042468103f   // 2*pi/64

typedef short s16x8 __attribute__((ext_vector_type(8)));
typedef float f32x4 __attribute__((ext_vector_type(4)));
typedef unsigned short u16x4 __attribute__((ext_vector_type(4)));

__device__ __forceinline__ unsigned short f2bf(float f) {
    unsigned int u = __float_as_uint(f);
    unsigned int r = (u + 0x7FFFu + ((u >> 16) & 1u)) >> 16;
    return (unsigned short)r;
}
__device__ __forceinline__ float bf2f(unsigned short s) {
    unsigned int u = ((unsigned int)s) << 16;
    return __uint_as_float(u);
}
__device__ __forceinline__ float2 cmul(float2 a, float2 b) {
    return make_float2(a.x * b.x - a.y * b.y, a.x * b.y + a.y * b.x);
}
__device__ __forceinline__ float2 cadd(float2 a, float2 b) { return make_float2(a.x + b.x, a.y + b.y); }
__device__ __forceinline__ float2 csub(float2 a, float2 b) { return make_float2(a.x - b.x, a.y - b.y); }
__device__ __forceinline__ unsigned int packbf(float re, float im) {
    return (unsigned int)f2bf(re) | ((unsigned int)f2bf(im) << 16);
}
__device__ __forceinline__ float2 unpackbf(unsigned int v) {
    return make_float2(bf2f((unsigned short)(v & 0xffff)), bf2f((unsigned short)(v >> 16)));
}

// LDS bank swizzle for the radix-2 tap FFT (involution)
#define SW(j) ((j) ^ (((j) >> 2) & 12) ^ (((j) >> 6) & 3))
// Padded index for the radix-8 conv FFT buffer
#define PD(j) ((j) + ((j) >> 4))

// ---------------- workspace layout (float offsets) ----------------
static const size_t O_P    = 0;          // psf taps; later SP_bf
static const size_t O_PSFH = 786432;     // psf-hat; later pre_w_bf + post_w_bf
static const size_t O_PART = 1376256;    // sn column-sum partials
static const size_t O_QH   = 1597440;    // q-hat
static const size_t O_X    = 1598240;    // x_bf [0,6291456) + Wf1 + Wi1
static const size_t O_XT   = 7897888;    // xT_bf [pre_proj -> sparse]
static const size_t O_XH   = 14189344;   // XHb u32 [dft -> conv]; CE_bf at +6488064
static const size_t O_YH   = 27157280;   // emb_bf [cvt -> ln]; YHb u32 at +6291456
static const size_t O_SPE  = 40146080;   // phf early; spe_bf later; G_bf at +3145728
static const size_t O_V    = 52728992;
static const size_t O_UR   = 52730016;
static const size_t O_SIG  = 52731040;   // inv_sigma + q[768] after

// ---------------- psf softmax over 2047 taps (1023 are zeros) ----------------
__global__ __launch_bounds__(256) void k_psf_softmax(const float* __restrict__ psfs,
                                                     float* __restrict__ p,
                                                     float* __restrict__ q) {
    int he = blockIdx.x;            // h*64+e
    int h = he >> 6, e = he & 63;
    int tid = threadIdx.x;
    float ev[4];
    float s = 0.f;
#pragma unroll
    for (int i = 0; i < 4; ++i) {
        int t = tid + 256 * i;
        float v = psfs[((size_t)h * 2047 + t) * 64 + e];
        ev[i] = expf(v);
        s += ev[i];
    }
    __shared__ float red[256];
    red[tid] = s; __syncthreads();
    for (int st = 128; st > 0; st >>= 1) {
        if (tid < st) red[tid] += red[tid + st];
        __syncthreads();
    }
    float denom = red[0] + 1023.0f;
    float inv = 1.0f / denom;
#pragma unroll
    for (int i = 0; i < 4; ++i) {
        int t = tid + 256 * i;
        p[((size_t)h * 1024 + t) * 64 + e] = ev[i] * inv;
    }
    if (tid == 0) q[he] = inv;
}

// ---------------- DFT over head-dim of psf taps (4 t per block) ----------------
__global__ __launch_bounds__(256) void k_psf_dft(const float* __restrict__ p,
                                                 float* __restrict__ psfh) {
    int blk = blockIdx.x;           // h*256 + tb
    int h = blk >> 8, tb = blk & 255;
    int t0 = tb * 4;
    int tid = threadIdx.x;
    int w = tid >> 6, lane = tid & 63;
    __shared__ float pv[4][64], cc[64], ssn[64];
    if (tid < 64) {
        float ang = TWOPI_64 * tid;
        cc[tid] = cosf(ang); ssn[tid] = sinf(ang);
    }
    pv[w][lane] = p[((size_t)h * 1024 + t0 + w) * 64 + lane];
    __syncthreads();
    if (lane < NK) {
        float re = 0.f, im = 0.f;
#pragma unroll 8
        for (int e = 0; e < 64; ++e) {
            int j = (lane * e) & 63;
            float v = pv[w][e];
            re += v * cc[j];
            im -= v * ssn[j];
        }
        size_t o = (((size_t)h * NK + lane) * 1024 + t0 + w) * 2;
        psfh[o] = re; psfh[o + 1] = im;
    }
}

// ---------------- DFT of uniform tap value q[h][e] ----------------
__global__ __launch_bounds__(64) void k_q_dft(const float* __restrict__ q,
                                              float* __restrict__ qh) {
    int h = blockIdx.x;
    int tid = threadIdx.x;
    __shared__ float qv[64], cc[64], ssn[64];
    qv[tid] = q[h * 64 + tid];
    float ang = TWOPI_64 * tid;
    cc[tid] = cosf(ang); ssn[tid] = sinf(ang);
    __syncthreads();
    if (tid < NK) {
        float re = 0.f, im = 0.f;
        for (int e = 0; e < 64; ++e) {
            int j = (tid * e) & 63;
            re += qv[e] * cc[j];
            im -= qv[e] * ssn[j];
        }
        qh[(h * NK + tid) * 2] = re;
        qh[(h * NK + tid) * 2 + 1] = im;
    }
}

// 512-entry tw table for the tap FFT (w2 computed as w1^2)
__device__ __forceinline__ void build_tw512(float2* tw, int tid) {
#pragma unroll
    for (int it = 0; it < 2; ++it) {
        int j = tid + it * 256;
        float a = (float)j * 3.0679615757712823e-3f;   // 2*pi/2048
        float sv, cv;
        __sincosf(a, &sv, &cv);
        tw[j] = make_float2(cv, -sv);
    }
}

// 1024-entry tw table for the conv FFT (direct w2/w4 lookups)
__device__ __forceinline__ void build_tw1024(float2* tw, int tid) {
#pragma unroll
    for (int it = 0; it < 4; ++it) {
        int j = tid + it * 256;
        float a = (float)j * 3.0679615757712823e-3f;   // 2*pi/2048
        float sv, cv;
        __sincosf(a, &sv, &cv);
        tw[j] = make_float2(cv, -sv);
    }
}

// ---------------- fused radix-2 stage-pair (swizzled LDS, w2 = w1^2) — tap FFT ----------------
__device__ __forceinline__ void fft_pair(const float2* __restrict__ X,
                                         float2* __restrict__ Y,
                                         const float2* __restrict__ tw,
                                         int tid, int m) {
#pragma unroll
    for (int it = 0; it < 2; ++it) {
        int i = tid + it * 256;
        int r = i & (m - 1);
        int am = i - r;
        float2 w1 = tw[am];
        float2 w1b = make_float2(w1.y, -w1.x);
        float2 w2 = cmul(w1, w1);
        float2 x0 = X[SW(i)], x1 = X[SW(i + 512)], x2 = X[SW(i + 1024)], x3 = X[SW(i + 1536)];
        float2 y0 = cadd(x0, x2);
        float2 y1 = cmul(csub(x0, x2), w1);
        float2 y2 = cadd(x1, x3);
        float2 y3 = cmul(csub(x1, x3), w1b);
        int o = 4 * am + r;
        Y[SW(o)] = cadd(y0, y2);
        Y[SW(o + m)] = cadd(y1, y3);
        Y[SW(o + 2 * m)] = cmul(csub(y0, y2), w2);
        Y[SW(o + 3 * m)] = cmul(csub(y1, y3), w2);
    }
}

// ---------------- FFT of tap vector per (h,k) (radix-2 pairs) ----------------
__global__ __launch_bounds__(256) void k_tap_fft(const float* __restrict__ psfh,
                                                 const float* __restrict__ qh,
                                                 float* __restrict__ phf) {
    __shared__ float2 A[2048], B[2048], tw[512];
    int hk = blockIdx.x, tid = threadIdx.x;
    build_tw512(tw, tid);
    float2 qv = make_float2(qh[hk * 2], qh[hk * 2 + 1]);
    const float2* Pg = (const float2*)(psfh + (size_t)hk * 2048);
    __syncthreads();
#pragma unroll
    for (int it = 0; it < 2; ++it) {
        int i = tid + it * 256;
        float2 x0 = Pg[i], x1 = Pg[i + 512];
        float2 x2 = (i == 0) ? make_float2(0.f, 0.f) : qv;
        float2 x3 = qv;
        float2 w1 = tw[i];
        float2 w1b = make_float2(w1.y, -w1.x);
        float2 w2 = cmul(w1, w1);
        float2 y0 = cadd(x0, x2);
        float2 y1 = cmul(csub(x0, x2), w1);
        float2 y2 = cadd(x1, x3);
        float2 y3 = cmul(csub(x1, x3), w1b);
        int o = 4 * i;
        A[SW(o)] = cadd(y0, y2);
        A[SW(o + 1)] = cadd(y1, y3);
        A[SW(o + 2)] = cmul(csub(y0, y2), w2);
        A[SW(o + 3)] = cmul(csub(y1, y3), w2);
    }
    __syncthreads();
    fft_pair(A, B, tw, tid, 4);   __syncthreads();
    fft_pair(B, A, tw, tid, 16);  __syncthreads();
    fft_pair(A, B, tw, tid, 64);  __syncthreads();
    fft_pair(B, A, tw, tid, 256); __syncthreads();
    float2* out = (float2*)(phf + (size_t)hk * 4096);
#pragma unroll
    for (int it = 0; it < 4; ++it) {
        int t = tid + it * 256;
        float2 lo = A[SW(t)], hi = A[SW(t + 1024)];
        out[t] = cadd(lo, hi);
        out[t + 1024] = csub(lo, hi);
    }
}

// ---------------- radix-8 triple: three radix-2 Stockham stages in registers ----------------
__device__ __forceinline__ void triple_tail(float2 z0, float2 z1, float2 z2, float2 z3,
                                            float2 zz0, float2 zz1, float2 zz2, float2 zz3,
                                            float2 w2, float2 w4, float2* o) {
    float2 w2b = make_float2(w2.y, -w2.x);
    float2 a0 = cadd(z0, z2),   a2 = cmul(csub(z0, z2), w2);
    float2 b0 = cadd(z1, z3),   b2 = cmul(csub(z1, z3), w2b);
    float2 a1 = cadd(zz0, zz2), a3 = cmul(csub(zz0, zz2), w2);
    float2 b1 = cadd(zz1, zz3), b3 = cmul(csub(zz1, zz3), w2b);
    o[0] = cadd(a0, b0); o[4] = cmul(csub(a0, b0), w4);
    o[1] = cadd(a1, b1); o[5] = cmul(csub(a1, b1), w4);
    o[2] = cadd(a2, b2); o[6] = cmul(csub(a2, b2), w4);
    o[3] = cadd(a3, b3); o[7] = cmul(csub(a3, b3), w4);
}

// 1024-entry-table variant: all twiddles are direct lookups (am <= 255 -> 4am <= 1020)
__device__ __forceinline__ void fft_triple_lut(const float2* x, const float2* __restrict__ tw,
                                               int am, float2* o) {
    float2 w10 = tw[am], w11 = tw[am + 256];
    float2 w2 = tw[2 * am], w4 = tw[4 * am];
    float2 w10b = make_float2(w10.y, -w10.x), w11b = make_float2(w11.y, -w11.x);
    float2 z0 = cadd(x[0], x[4]), z1 = cadd(x[1], x[5]);
    float2 z2 = cadd(x[2], x[6]), z3 = cadd(x[3], x[7]);
    float2 zz0 = cmul(csub(x[0], x[4]), w10);
    float2 zz1 = cmul(csub(x[1], x[5]), w11);
    float2 zz2 = cmul(csub(x[2], x[6]), w10b);
    float2 zz3 = cmul(csub(x[3], x[7]), w11b);
    triple_tail(z0, z1, z2, z3, zz0, zz1, zz2, zz3, w2, w4, o);
}

// ---------------- per-(b,h,k) conv via circular-2048 FFT — radix-8, 1024-entry tw ----------------
__global__ __launch_bounds__(256) void k_conv_fft(const unsigned int* __restrict__ XHb,
                                                  const float* __restrict__ PHF,
                                                  unsigned int* __restrict__ YHb) {
    __shared__ float2 S[2176], tw[1024];
    int bhk = blockIdx.x, tid = threadIdx.x;
    int hk = bhk % NHK;
    build_tw1024(tw, tid);
    const unsigned int* Xg = XHb + (size_t)bhk * 1024;
    float2 x[8], o[8];
#pragma unroll
    for (int k = 0; k < 4; ++k) x[k] = unpackbf(Xg[tid + 256 * k]);
    __syncthreads();                              // tw ready
    // fwd R1: m=1 (am=tid), upper half zero -> z=x, zz=x*w
    {
        float2 w10 = tw[tid], w11 = tw[tid + 256];
        float2 w2 = tw[2 * tid], w4 = tw[4 * tid];
        float2 w10b = make_float2(w10.y, -w10.x), w11b = make_float2(w11.y, -w11.x);
        float2 zz0 = cmul(x[0], w10), zz1 = cmul(x[1], w11);
        float2 zz2 = cmul(x[2], w10b), zz3 = cmul(x[3], w11b);
        triple_tail(x[0], x[1], x[2], x[3], zz0, zz1, zz2, zz3, w2, w4, o);
    }
#pragma unroll
    for (int k = 0; k < 8; ++k) S[PD(8 * tid + k)] = o[k];
    __syncthreads();
    // fwd R2: m=8
    {
        int r = tid & 7, am = tid - r;
#pragma unroll
        for (int k = 0; k < 8; ++k) x[k] = S[PD(tid + 256 * k)];
        __syncthreads();
        fft_triple_lut(x, tw, am, o);
        int base = 8 * am + r;
#pragma unroll
        for (int k = 0; k < 8; ++k) S[PD(base + 8 * k)] = o[k];
    }
    __syncthreads();
    // fwd R3: m=64
    {
        int r = tid & 63, am = tid - r;
#pragma unroll
        for (int k = 0; k < 8; ++k) x[k] = S[PD(tid + 256 * k)];
        __syncthreads();
        fft_triple_lut(x, tw, am, o);
        int base = 8 * am + r;
#pragma unroll
        for (int k = 0; k < 8; ++k) S[PD(base + 64 * k)] = o[k];
    }
    __syncthreads();
    // fwd final pair (trivial twiddles) + pointwise multiply + conj (inverse trick)
    const float2* P = (const float2*)(PHF + (size_t)hk * 4096);
    float2 v[8];
#pragma unroll
    for (int it = 0; it < 2; ++it) {
        int i2 = tid + 256 * it;
        float2 g0 = S[PD(i2)], g1 = S[PD(i2 + 512)], g2 = S[PD(i2 + 1024)], g3 = S[PD(i2 + 1536)];
        float2 y0 = cadd(g0, g2), y1 = csub(g0, g2);
        float2 y2 = cadd(g1, g3);
        float2 d13 = csub(g1, g3);
        float2 y3 = make_float2(d13.y, -d13.x);
        float2 F0 = cadd(y0, y2);
        float2 F1 = cadd(y1, y3);
        float2 F2 = csub(y0, y2);
        float2 F3 = csub(y1, y3);
        float2 V0 = cmul(F0, P[i2]);
        float2 V1 = cmul(F1, P[i2 + 512]);
        float2 V2 = cmul(F2, P[i2 + 1024]);
        float2 V3 = cmul(F3, P[i2 + 1536]);
        v[it]     = make_float2(V0.x, -V0.y);
        v[it + 2] = make_float2(V1.x, -V1.y);
        v[it + 4] = make_float2(V2.x, -V2.y);
        v[it + 6] = make_float2(V3.x, -V3.y);
    }
    __syncthreads();
    // inv R1: m=1 fully in registers
    fft_triple_lut(v, tw, tid, o);
#pragma unroll
    for (int k = 0; k < 8; ++k) S[PD(8 * tid + k)] = o[k];
    __syncthreads();
    // inv R2: m=8
    {
        int r = tid & 7, am = tid - r;
#pragma unroll
        for (int k = 0; k < 8; ++k) x[k] = S[PD(tid + 256 * k)];
        __syncthreads();
        fft_triple_lut(x, tw, am, o);
        int base = 8 * am + r;
#pragma unroll
        for (int k = 0; k < 8; ++k) S[PD(base + 8 * k)] = o[k];
    }
    __syncthreads();
    // inv R3: m=64
    {
        int r = tid & 63, am = tid - r;
#pragma unroll
        for (int k = 0; k < 8; ++k) x[k] = S[PD(tid + 256 * k)];
        __syncthreads();
        fft_triple_lut(x, tw, am, o);
        int base = 8 * am + r;
#pragma unroll
        for (int k = 0; k < 8; ++k) S[PD(base + 64 * k)] = o[k];
    }
    __syncthreads();
    // inv final pair: only s<1024 needed; scale + conj; bf16 pack
    unsigned int* Yg = YHb + (size_t)bhk * 1024;
    const float inv_n = 1.0f / 2048.0f;
#pragma unroll
    for (int it = 0; it < 2; ++it) {
        int i2 = tid + 256 * it;
        float2 g0 = S[PD(i2)], g1 = S[PD(i2 + 512)], g2 = S[PD(i2 + 1024)], g3 = S[PD(i2 + 1536)];
        float2 s02 = cadd(g0, g2), d02 = csub(g0, g2);
        float2 s13 = cadd(g1, g3);
        float2 d13 = csub(g1, g3);
        float2 mj13 = make_float2(d13.y, -d13.x);
        float2 o0 = cadd(s02, s13);
        float2 o1 = cadd(d02, mj13);
        Yg[i2] = packbf(o0.x * inv_n, -o0.y * inv_n);
        Yg[i2 + 512] = packbf(o1.x * inv_n, -o1.y * inv_n);
    }
}

// ---------------- build both per-head DFT blocks ----------------
__global__ __launch_bounds__(64) void k_build_w(unsigned short* __restrict__ Wf,
                                                unsigned short* __restrict__ Wi) {
    int m = blockIdx.x;                  // 0..255
    int c = threadIdx.x;                 // 0..63
    if (m < 128) {
        float val = 0.f;
        if (m < 66) {
            int k = m >> 1, od = m & 1;
            int j = (k * c) & 63;
            float ang = TWOPI_64 * (float)j;
            val = od ? -sinf(ang) : cosf(ang);
        }
        Wf[m * 64 + c] = f2bf(val);
    } else {
        int mm = m - 128;
        float val = 0.f;
        if (mm < 64) {
            int d = mm;
            int k, od;
            float ck;
            if (c == 0)      { k = 0;  od = 0; ck = 1.f / 64.f; }
            else if (c == 1) { k = 32; od = 0; ck = 1.f / 64.f; }
            else             { k = c >> 1; od = c & 1; ck = 2.f / 64.f; }
            int j = (k * d) & 63;
            float ang = TWOPI_64 * (float)j;
            val = od ? -sinf(ang) * ck : cosf(ang) * ck;
        }
        Wi[mm * 64 + c] = f2bf(val);
    }
}

// ---------------- BK=64 MFMA core (bf16 sources, 256 threads) ----------------
__device__ __forceinline__ void mfma_core64(const unsigned short* __restrict__ gA0,
                                            const unsigned short* __restrict__ gB0,
                                            int nkt,
                                            unsigned short* __restrict__ As,
                                            unsigned short* __restrict__ Bs,
                                            int tid, int lane, int wr, int wc,
                                            f32x4 acc[4][4]) {
    int r0 = tid >> 1, hs = (tid & 1) << 2;
    int wbase = r0 * 64;
    int swr = r0 & 7;
    int kg = lane >> 4, cl = lane & 15;
    int fra[8], frb[8];
#pragma unroll
    for (int kk = 0; kk < 2; ++kk)
#pragma unroll
        for (int i = 0; i < 4; ++i) {
            int ra = wr * 64 + i * 16 + cl;
            fra[kk * 4 + i] = ra * 64 + (((kk * 4 + kg) ^ (ra & 7)) << 3);
            int rb = wc * 64 + i * 16 + cl;
            frb[kk * 4 + i] = rb * 64 + (((kk * 4 + kg) ^ (rb & 7)) << 3);
        }
    s16x8 a[4], b[4];
#pragma unroll
    for (int l = 0; l < 4; ++l) {
        a[l] = *(const s16x8*)(gA0 + l * 8);
        b[l] = *(const s16x8*)(gB0 + l * 8);
    }
    for (int kt = 0; kt < nkt; ++kt) {
        __syncthreads();
#pragma unroll
        for (int l = 0; l < 4; ++l) {
            *(s16x8*)&As[wbase + (((hs + l) ^ swr) << 3)] = a[l];
            *(s16x8*)&Bs[wbase + (((hs + l) ^ swr) << 3)] = b[l];
        }
        __syncthreads();
        if (kt + 1 < nkt) {
            size_t ko = (size_t)(kt + 1) * 64;
#pragma unroll
            for (int l = 0; l < 4; ++l) {
                a[l] = *(const s16x8*)(gA0 + ko + l * 8);
                b[l] = *(const s16x8*)(gB0 + ko + l * 8);
            }
        }
#pragma unroll
        for (int kk = 0; kk < 2; ++kk) {
            s16x8 af[4], bfr[4];
#pragma unroll
            for (int i = 0; i < 4; ++i) af[i] = *(const s16x8*)&As[fra[kk * 4 + i]];
#pragma unroll
            for (int i = 0; i < 4; ++i) bfr[i] = *(const s16x8*)&Bs[frb[kk * 4 + i]];
#pragma unroll
            for (int mi = 0; mi < 4; ++mi)
#pragma unroll
                for (int ni = 0; ni < 4; ++ni)
                    acc[mi][ni] = __builtin_amdgcn_mfma_f32_16x16x32_bf16(af[mi], bfr[ni], acc[mi][ni], 0, 0, 0);
        }
    }
}

// ---------------- projection GEMM: BM=64,BN=256,BK=64, 512 threads (8 waves 2x4) ----------------
// LDS-staged coalesced epilogue; optional fused xT emission (pre-projection).
__global__ __launch_bounds__(512) void k_mfma_proj(const unsigned short* __restrict__ A,
                                                   const unsigned short* __restrict__ W,
                                                   const float* __restrict__ bias,
                                                   unsigned short* __restrict__ C,
                                                   unsigned short* __restrict__ XT) {
    const int K = Dn, N = Dn;
    int n0 = blockIdx.x * 256, m0 = blockIdx.y * 64;
    int tid = threadIdx.x;
    int lane = tid & 63, wave = tid >> 6;    // 0..7
    int wr = wave >> 2, wc = wave & 3;       // 2 x 4 (wave tile: 32m x 64n)
    __shared__ __align__(16) unsigned short LDSu[20480];   // A[0..4095] + B[4096..20479]
    unsigned short* As = LDSu;
    unsigned short* Bs = LDSu + 4096;
    f32x4 acc[2][4] = {};
    int ra0 = tid >> 3, sa0 = tid & 7;       // A: 64 rows x 8 slots, 1 slot/thread
    int rb0 = tid >> 1, sb0 = (tid & 1) * 4; // B: 256 rows, 4 slots/thread
    const unsigned short* gA = A + (size_t)(m0 + ra0) * K + sa0 * 8;
    const unsigned short* gB = W + (size_t)(n0 + rb0) * K + sb0 * 8;
    int kg = lane >> 4, cl = lane & 15;
    int fra[4], frb[8];
#pragma unroll
    for (int kk = 0; kk < 2; ++kk) {
#pragma unroll
        for (int i = 0; i < 2; ++i) {
            int ra = wr * 32 + i * 16 + cl;
            fra[kk * 2 + i] = ra * 64 + (((kk * 4 + kg) ^ (ra & 7)) << 3);
        }
#pragma unroll
        for (int i = 0; i < 4; ++i) {
            int rb = wc * 64 + i * 16 + cl;
            frb[kk * 4 + i] = rb * 64 + (((kk * 4 + kg) ^ (rb & 7)) << 3);
        }
    }
    s16x8 a0, b[4];
    a0 = *(const s16x8*)(gA);
#pragma unroll
    for (int l = 0; l < 4; ++l) b[l] = *(const s16x8*)(gB + l * 8);
    const int nkt = K >> 6;   // 12
    for (int kt = 0; kt < nkt; ++kt) {
        __syncthreads();
        *(s16x8*)&As[ra0 * 64 + ((sa0 ^ (ra0 & 7)) << 3)] = a0;
#pragma unroll
        for (int l = 0; l < 4; ++l)
            *(s16x8*)&Bs[rb0 * 64 + (((sb0 + l) ^ (rb0 & 7)) << 3)] = b[l];
        __syncthreads();
        if (kt + 1 < nkt) {
            size_t ko = (size_t)(kt + 1) * 64;
            a0 = *(const s16x8*)(gA + ko);
#pragma unroll
            for (int l = 0; l < 4; ++l) b[l] = *(const s16x8*)(gB + ko + l * 8);
        }
#pragma unroll
        for (int kk = 0; kk < 2; ++kk) {
            s16x8 af[2], bfr[4];
#pragma unroll
            for (int i = 0; i < 2; ++i) af[i] = *(const s16x8*)&As[fra[kk * 2 + i]];
#pragma unroll
            for (int i = 0; i < 4; ++i) bfr[i] = *(const s16x8*)&Bs[frb[kk * 4 + i]];
#pragma unroll
            for (int mi = 0; mi < 2; ++mi)
#pragma unroll
                for (int ni = 0; ni < 4; ++ni)
                    acc[mi][ni] = __builtin_amdgcn_mfma_f32_16x16x32_bf16(af[mi], bfr[ni], acc[mi][ni], 0, 0, 0);
        }
    }
    // ---- LDS-staged coalesced epilogue ----
    __syncthreads();                          // all MFMA LDS reads done; overlay staging
    unsigned short* ST = LDSu + wave * 2304;  // per-wave 32 rows x 72 (pad; 16B-aligned)
#pragma unroll
    for (int ni = 0; ni < 4; ++ni) {
        int gn = n0 + wc * 64 + ni * 16 + cl;
        float bv = bias[gn];
#pragma unroll
        for (int mi = 0; mi < 2; ++mi) {
            f32x4 v = acc[mi][ni];
#pragma unroll
            for (int ri = 0; ri < 4; ++ri)
                ST[(mi * 16 + kg * 4 + ri) * 72 + ni * 16 + cl] = f2bf(v[ri] + bv);
        }
    }
    __syncthreads();
    // C rows: lane pair covers one row (128B contiguous per 2 lanes)
    {
        int r = lane >> 1, ch = (lane & 1) * 32;
        int gm = m0 + wr * 32 + r;
        const unsigned short* src = ST + r * 72 + ch;
        unsigned short* dst = C + (size_t)gm * N + n0 + wc * 64 + ch;
#pragma unroll
        for (int j = 0; j < 4; ++j)
            *(s16x8*)(dst + j * 8) = *(const s16x8*)(src + j * 8);
    }
    // xT emission (pre-projection): lane reads one column of staged tile
    if (XT) {
        int gn = n0 + wc * 64 + lane;
        unsigned short tmp[32];
#pragma unroll
        for (int r = 0; r < 32; ++r) tmp[r] = ST[r * 72 + lane];
        int b0 = m0 >> 10;
        int t0 = (m0 & 1023) + wr * 32;
        unsigned short* dst = XT + ((size_t)b0 * Dn + gn) * Ln + t0;
#pragma unroll
        for (int j = 0; j < 4; ++j)
            *(s16x8*)(dst + j * 8) = *(const s16x8*)&tmp[j * 8];
    }
}

// ---------------- per-head forward DFT GEMM -> bf16 complex planes ----------------
__global__ __launch_bounds__(256) void k_mfma_dft_h(const unsigned short* __restrict__ Wf1,
                                                    const unsigned short* __restrict__ Xb,
                                                    unsigned int* __restrict__ XHb) {
    int n0 = blockIdx.x * 128;          // x-row tile
    int h = blockIdx.y;                 // head
    int tid = threadIdx.x;
    int lane = tid & 63, wave = tid >> 6;
    int wr = wave >> 1, wc = wave & 1;
    __shared__ __align__(16) unsigned short As[8192], Bs[8192];
    f32x4 acc[4][4] = {};
    int r0 = tid >> 1, hs = (tid & 1) << 2;
    const unsigned short* gA0 = Wf1 + r0 * 64 + hs * 8;
    const unsigned short* gB0 = Xb + (size_t)(n0 + r0) * Dn + h * 64 + hs * 8;
    mfma_core64(gA0, gB0, 1, As, Bs, tid, lane, wr, wc, acc);
    int kg = lane >> 4, cl = lane & 15;
#pragma unroll
    for (int ni = 0; ni < 4; ++ni) {
        int gn = n0 + wc * 64 + ni * 16 + cl;   // global x row
        int b = gn >> 10, u = gn & 1023;
#pragma unroll
        for (int mi = 0; mi < 4; ++mi) {
            int gmb = wr * 64 + mi * 16 + kg * 4;
            f32x4 v = acc[mi][ni];
#pragma unroll
            for (int rp = 0; rp < 2; ++rp) {
                int m = gmb + rp * 2;           // even: pair (re,im) of bin m>>1
                if (m < 66) {
                    size_t plane = (size_t)(b * Hn + h) * NK + (m >> 1);
                    XHb[plane * 1024 + u] = packbf(v[rp * 2], v[rp * 2 + 1]);
                }
            }
        }
    }
}

// ---------------- per-head inverse DFT + GELU GEMM (fused YHb transpose staging) ----------------
__global__ __launch_bounds__(256) void k_mfma_idft_h(const unsigned int* __restrict__ YHb,
                                                     const unsigned short* __restrict__ Wi1,
                                                     unsigned short* __restrict__ G) {
    int m0 = blockIdx.x * 128;          // global row tile (b*1024+u0)
    int h = blockIdx.y;                 // head
    int b = m0 >> 10, u0 = m0 & 1023;
    int tid = threadIdx.x;
    int lane = tid & 63, wave = tid >> 6;
    int wr = wave >> 1, wc = wave & 1;
    __shared__ __align__(16) unsigned short As[8192], Bs[8192];
    int planeBase = (b * Hn + h) * NK;
#pragma unroll
    for (int i = 0; i < 17; ++i) {
        int idx = tid + i * 256;        // 33 k-planes x 128 rows
        if (idx < 4224) {
            int k = idx >> 7, uo = idx & 127;
            unsigned int v = YHb[(size_t)(planeBase + k) * 1024 + u0 + uo];
            unsigned short lo = (unsigned short)(v & 0xffff);
            unsigned short hi = (unsigned short)(v >> 16);
            int sw = uo & 7;
            int rb = uo * 64;
            if (k == 0) {
                As[rb + (sw << 3) + 0] = lo;
            } else if (k == 32) {
                As[rb + (sw << 3) + 1] = lo;
            } else {
                int c0 = 2 * k, c1 = 2 * k + 1;
                As[rb + (((c0 >> 3) ^ sw) << 3) + (c0 & 7)] = lo;
                As[rb + (((c1 >> 3) ^ sw) << 3) + (c1 & 7)] = hi;
            }
        }
    }
    {
        int r0 = tid >> 1, hs = (tid & 1) << 2;
        int swr = r0 & 7;
        const unsigned short* gB0 = Wi1 + r0 * 64 + hs * 8;
#pragma unroll
        for (int l = 0; l < 4; ++l)
            *(s16x8*)&Bs[r0 * 64 + (((hs + l) ^ swr) << 3)] = *(const s16x8*)(gB0 + l * 8);
    }
    __syncthreads();
    f32x4 acc[4][4] = {};
    int kg = lane >> 4, cl = lane & 15;
#pragma unroll
    for (int kk = 0; kk < 2; ++kk) {
        s16x8 af[4], bfr[4];
#pragma unroll
        for (int i = 0; i < 4; ++i) {
            int ra = wr * 64 + i * 16 + cl;
            af[i] = *(const s16x8*)&As[ra * 64 + (((kk * 4 + kg) ^ (ra & 7)) << 3)];
            int rbw = wc * 64 + i * 16 + cl;
            bfr[i] = *(const s16x8*)&Bs[rbw * 64 + (((kk * 4 + kg) ^ (rbw & 7)) << 3)];
        }
#pragma unroll
        for (int mi = 0; mi < 4; ++mi)
#pragma unroll
            for (int ni = 0; ni < 4; ++ni)
                acc[mi][ni] = __builtin_amdgcn_mfma_f32_16x16x32_bf16(af[mi], bfr[ni], acc[mi][ni], 0, 0, 0);
    }
#pragma unroll
    for (int ni = 0; ni < 4; ++ni) {
        int gn = wc * 64 + ni * 16 + cl;    // d index (valid < 64)
        if (gn < 64) {
#pragma unroll
            for (int mi = 0; mi < 4; ++mi) {
                int gm = m0 + wr * 64 + mi * 16 + kg * 4;
                f32x4 v = acc[mi][ni];
#pragma unroll
                for (int ri = 0; ri < 4; ++ri) {
                    float c = v[ri];
                    float g = c * 0.5f * (1.0f + erff(c * 0.70710678118f));
                    G[(size_t)(gm + ri) * Dn + h * 64 + gn] = f2bf(g);
                }
            }
        }
    }
}

// ---------------- sparse: spe_b = (tril(SP)/sigma) @ x_b — BM=128,BN=256, 512 threads ----------------
__global__ __launch_bounds__(512) void k_mfma_sparse(const unsigned short* __restrict__ SP,
                                                     const unsigned short* __restrict__ XT,
                                                     const float* __restrict__ sigbuf,
                                                     unsigned short* __restrict__ C) {
    int bx = blockIdx.x;
    int mt = bx & 7, nt = (bx >> 3) % 3, b = bx / 24;
    int m0 = mt * 128, n0 = nt * 256;
    const unsigned short* Xb = XT + (size_t)b * Dn * Ln;
    unsigned short* Cb = C + (size_t)b * Ln * Dn;
    int tid = threadIdx.x;
    int lane = tid & 63, wave = tid >> 6;
    int wr = wave >> 2, wc = wave & 3;       // 2 x 4
    __shared__ __align__(16) unsigned short As[8192], Bs[16384];
    f32x4 acc[4][4] = {};
    int ra0 = tid >> 2, sa0 = (tid & 3) * 2;
    int rb0 = tid >> 1, sb0 = (tid & 1) * 4;
    const unsigned short* gA = SP + (size_t)(m0 + ra0) * Ln + sa0 * 8;
    const unsigned short* gB = Xb + (size_t)(n0 + rb0) * Ln + sb0 * 8;
    int kg = lane >> 4, cl = lane & 15;
    int fra[8], frb[8];
#pragma unroll
    for (int kk = 0; kk < 2; ++kk)
#pragma unroll
        for (int i = 0; i < 4; ++i) {
            int ra = wr * 64 + i * 16 + cl;
            fra[kk * 4 + i] = ra * 64 + (((kk * 4 + kg) ^ (ra & 7)) << 3);
            int rb = wc * 64 + i * 16 + cl;
            frb[kk * 4 + i] = rb * 64 + (((kk * 4 + kg) ^ (rb & 7)) << 3);
        }
    s16x8 a[2], b2[4];
#pragma unroll
    for (int l = 0; l < 2; ++l) a[l] = *(const s16x8*)(gA + l * 8);
#pragma unroll
    for (int l = 0; l < 4; ++l) b2[l] = *(const s16x8*)(gB + l * 8);
    int nkt = 2 * mt + 2;            // only k-tiles with t0 <= m0+127 (tril)
    for (int kt = 0; kt < nkt; ++kt) {
        __syncthreads();
#pragma unroll
        for (int l = 0; l < 2; ++l)
            *(s16x8*)&As[ra0 * 64 + (((sa0 + l) ^ (ra0 & 7)) << 3)] = a[l];
#pragma unroll
        for (int l = 0; l < 4; ++l)
            *(s16x8*)&Bs[rb0 * 64 + (((sb0 + l) ^ (rb0 & 7)) << 3)] = b2[l];
        __syncthreads();
        if (kt + 1 < nkt) {
            size_t ko = (size_t)(kt + 1) * 64;
#pragma unroll
            for (int l = 0; l < 2; ++l) a[l] = *(const s16x8*)(gA + ko + l * 8);
#pragma unroll
            for (int l = 0; l < 4; ++l) b2[l] = *(const s16x8*)(gB + ko + l * 8);
        }
#pragma unroll
        for (int kk = 0; kk < 2; ++kk) {
            s16x8 af[4], bfr[4];
#pragma unroll
            for (int i = 0; i < 4; ++i) af[i] = *(const s16x8*)&As[fra[kk * 4 + i]];
#pragma unroll
            for (int i = 0; i < 4; ++i) bfr[i] = *(const s16x8*)&Bs[frb[kk * 4 + i]];
#pragma unroll
            for (int mi = 0; mi < 4; ++mi)
#pragma unroll
                for (int ni = 0; ni < 4; ++ni)
                    acc[mi][ni] = __builtin_amdgcn_mfma_f32_16x16x32_bf16(af[mi], bfr[ni], acc[mi][ni], 0, 0, 0);
        }
    }
    float invs = sigbuf[0];
#pragma unroll
    for (int ni = 0; ni < 4; ++ni) {
        int gn = n0 + wc * 64 + ni * 16 + cl;
#pragma unroll
        for (int mi = 0; mi < 4; ++mi) {
            int gm = m0 + wr * 64 + mi * 16 + kg * 4;
            f32x4 v = acc[mi][ni];
#pragma unroll
            for (int ri = 0; ri < 4; ++ri)
                Cb[(size_t)(gm + ri) * Dn + gn] = f2bf(v[ri] * invs);
        }
    }
}

// ---------------- conversions ----------------
__global__ __launch_bounds__(256) void k_cvt_bf16(const float* __restrict__ in,
                                                  unsigned short* __restrict__ out, int n4) {
    int i = blockIdx.x * 256 + threadIdx.x;
    if (i < n4) {
        float4 v = ((const float4*)in)[i];
        u16x4 o;
        o[0] = f2bf(v.x); o[1] = f2bf(v.y); o[2] = f2bf(v.z); o[3] = f2bf(v.w);
        *(u16x4*)&out[(size_t)i * 4] = o;
    }
}

// ---------------- fused: spectral-norm column partial sums + tril bf16 conversion ----------------
__global__ __launch_bounds__(256) void k_sn_prep(const float* __restrict__ Wm,
                                                 float* __restrict__ partial,
                                                 unsigned short* __restrict__ SPb) {
    int b = blockIdx.x;               // rows [16b, 16b+16)
    int tid = threadIdx.x;
    int c0 = tid * 4;
    float4 s = make_float4(0.f, 0.f, 0.f, 0.f);
#pragma unroll
    for (int i = 0; i < 16; ++i) {
        int row = b * 16 + i;
        float4 v = *(const float4*)&Wm[(size_t)row * 1024 + c0];
        s.x += v.x; s.y += v.y; s.z += v.z; s.w += v.w;
        u16x4 o;
        o[0] = (c0 + 0 <= row) ? f2bf(v.x) : 0;
        o[1] = (c0 + 1 <= row) ? f2bf(v.y) : 0;
        o[2] = (c0 + 2 <= row) ? f2bf(v.z) : 0;
        o[3] = (c0 + 3 <= row) ? f2bf(v.w) : 0;
        *(u16x4*)&SPb[(size_t)row * 1024 + c0] = o;
    }
    *(float4*)&partial[(size_t)b * 1024 + c0] = s;
}

__global__ __launch_bounds__(1024) void k_sn_v2(const float* __restrict__ partial,
                                                float* __restrict__ v) {
    int j = threadIdx.x;
    float s = 0.f;
#pragma unroll 8
    for (int i = 0; i < 64; ++i) s += partial[(size_t)i * 1024 + j];
    s *= 0.03125f;
    __shared__ float red[1024];
    red[j] = s * s; __syncthreads();
    for (int st = 512; st > 0; st >>= 1) {
        if (j < st) red[j] += red[j + st];
        __syncthreads();
    }
    float nrm = sqrtf(red[0]);
    v[j] = s / (nrm + 1e-12f);
}

__global__ __launch_bounds__(64) void k_sn_u(const float* __restrict__ Wm,
                                             const float* __restrict__ v,
                                             float* __restrict__ ur) {
    int i = blockIdx.x;
    int lane = threadIdx.x;
    float s = 0.f;
    for (int j = lane; j < 1024; j += 64) s += Wm[(size_t)i * 1024 + j] * v[j];
#pragma unroll
    for (int off = 32; off > 0; off >>= 1) s += __shfl_down(s, off);
    if (lane == 0) ur[i] = s;
}

__global__ __launch_bounds__(1024) void k_sn_sigma(const float* __restrict__ ur,
                                                   float* __restrict__ sig) {
    int i = threadIdx.x;
    __shared__ float red[1024];
    float u = ur[i];
    red[i] = u * u; __syncthreads();
    for (int st = 512; st > 0; st >>= 1) {
        if (i < st) red[i] += red[i + st];
        __syncthreads();
    }
    if (i == 0) {
        float ss = red[0];
        float sigma = ss / (sqrtf(ss) + 1e-12f);
        sig[0] = 1.0f / sigma;
    }
}

// ---------------- final residual + LayerNorm (all-bf16 inputs) ----------------
__global__ __launch_bounds__(256) void k_final_ln(const unsigned short* __restrict__ CE,
                                                  const unsigned short* __restrict__ SE,
                                                  const unsigned short* __restrict__ EMB,
                                                  const float* __restrict__ g,
                                                  const float* __restrict__ be,
                                                  float* __restrict__ out) {
    int r = blockIdx.x;
    int tid = threadIdx.x;
    float y[3];
    float s = 0.f;
#pragma unroll
    for (int i = 0; i < 3; ++i) {
        int o = tid + i * 256;
        size_t idx = (size_t)r * 768 + o;
        y[i] = bf2f(CE[idx]) + bf2f(SE[idx]) + bf2f(EMB[idx]);
        s += y[i];
    }
    __shared__ float red[256];
    red[tid] = s; __syncthreads();
    for (int st = 128; st > 0; st >>= 1) {
        if (tid < st) red[tid] += red[tid + st];
        __syncthreads();
    }
    float mu = red[0] * (1.f / 768.f);
    __syncthreads();
    float vs = 0.f;
#pragma unroll
    for (int i = 0; i < 3; ++i) { float d = y[i] - mu; vs += d * d; }
    red[tid] = vs; __syncthreads();
    for (int st = 128; st > 0; st >>= 1) {
        if (tid < st) red[tid] += red[tid + st];
        __syncthreads();
    }
    float var = red[0] * (1.f / 768.f);
    float rstd = rsqrtf(var + 1e-12f);
#pragma unroll
    for (int i = 0; i < 3; ++i) {
        int o = tid + i * 256;
        size_t idx = (size_t)r * 768 + o;
        out[idx] = (y[i] - mu) * rstd * g[o] + be[o];
    }
}

extern "C" void kernel_launch(void* const* d_in, const int* in_sizes, int n_in,
                              void* d_out, int out_size, void* d_ws, size_t ws_size,
                              hipStream_t stream) {
    const float* emb     = (const float*)d_in[0];
    const float* pre_w   = (const float*)d_in[1];
    const float* pre_b   = (const float*)d_in[2];
    const float* psfs    = (const float*)d_in[3];
    const float* post_w  = (const float*)d_in[4];
    const float* post_b  = (const float*)d_in[5];
    const float* spmat   = (const float*)d_in[6];
    const float* ln_g    = (const float*)d_in[7];
    const float* ln_b    = (const float*)d_in[8];
    float* out = (float*)d_out;
    float* ws = (float*)d_ws;

    float* p      = ws + O_P;
    float* psfh   = ws + O_PSFH;
    float* part   = ws + O_PART;
    float* qh     = ws + O_QH;
    float* q      = ws + O_SIG + 8;
    float* phf    = ws + O_SPE;                       // alias (dead after conv)
    float* v      = ws + O_V;
    float* urw    = ws + O_UR;
    float* sig    = ws + O_SIG;

    unsigned int* XHb = (unsigned int*)(ws + O_XH);                 // [dft -> conv]
    unsigned int* YHb = (unsigned int*)(ws + O_YH + 6291456);       // [conv -> idft]
    unsigned short* emb_bf    = (unsigned short*)(ws + O_YH);       // [cvt -> final_ln]
    unsigned short* x_bf      = (unsigned short*)(ws + O_X);
    unsigned short* Wf1       = (unsigned short*)(ws + O_X + 6291456);      // [128][64]
    unsigned short* Wi1       = (unsigned short*)(ws + O_X + 6295552);      // [128][64]
    unsigned short* xT_bf     = (unsigned short*)(ws + O_XT);               // [pre_proj -> sparse]
    unsigned short* CE_bf     = (unsigned short*)(ws + O_XH + 6488064);     // past XHb span
    unsigned short* spe_bf    = (unsigned short*)(ws + O_SPE);              // over dead phf
    unsigned short* G_bf      = (unsigned short*)(ws + O_SPE + 3145728);    // disjoint
    unsigned short* SP_bf     = (unsigned short*)(ws + O_P);                // over dead p
    unsigned short* pre_w_bf  = (unsigned short*)(ws + O_PSFH);             // over dead psfh
    unsigned short* post_w_bf = (unsigned short*)(ws + O_PSFH + 294912);

    // PSF preprocessing
    k_psf_softmax<<<Hn * 64, 256, 0, stream>>>(psfs, p, q);
    k_psf_dft<<<Hn * 256, 256, 0, stream>>>(p, psfh);
    k_q_dft<<<Hn, 64, 0, stream>>>(q, qh);
    k_tap_fft<<<NHK, 256, 0, stream>>>(psfh, qh, phf);

    // spectral norm scalar (fused colsum + SP tril bf16)
    k_sn_prep<<<64, 256, 0, stream>>>(spmat, part, SP_bf);
    k_sn_v2<<<1, 1024, 0, stream>>>(part, v);
    k_sn_u<<<1024, 64, 0, stream>>>(spmat, v, urw);
    k_sn_sigma<<<1, 1024, 0, stream>>>(urw, sig);

    // bf16 conversions + DFT block builds
    k_cvt_bf16<<<576, 256, 0, stream>>>(pre_w, pre_w_bf, 147456);
    k_cvt_bf16<<<576, 256, 0, stream>>>(post_w, post_w_bf, 147456);
    k_cvt_bf16<<<12288, 256, 0, stream>>>(emb, emb_bf, 3145728);
    k_build_w<<<256, 64, 0, stream>>>(Wf1, Wi1);

    // pre-projection (BM=64, BN=256, coalesced epilogue) -> x bf16 + fused xT emission
    k_mfma_proj<<<dim3(3, 256), 512, 0, stream>>>(emb_bf, pre_w_bf, pre_b, x_bf, xT_bf);

    // head-dim DFT: per-head batched GEMM -> bf16 complex planes
    k_mfma_dft_h<<<dim3(128, Hn), 256, 0, stream>>>(Wf1, x_bf, XHb);

    // causal conv + uniform suffix via circular-2048 FFT (radix-8, 1024-entry tw LUT)
    k_conv_fft<<<Bn * NHK, 256, 0, stream>>>(XHb, phf, YHb);

    // inverse DFT + GELU: fused YHb transpose staging -> G bf16
    k_mfma_idft_h<<<dim3(128, Hn), 256, 0, stream>>>(YHb, Wi1, G_bf);

    // post-projection (BM=64, BN=256, coalesced epilogue) -> CE bf16
    k_mfma_proj<<<dim3(3, 256), 512, 0, stream>>>(G_bf, post_w_bf, post_b, CE_bf, nullptr);

    // sparse branch (BN=256, triangular k-loop) -> spe bf16 (over dead phf)
    k_mfma_sparse<<<384, 512, 0, stream>>>(SP_bf, xT_bf, sig, spe_bf);

    // residual + LayerNorm (all-bf16 inputs)
    k_final_ln<<<Bn * Ln, 256, 0, stream>>>(CE_bf, spe_bf, emb_bf, ln_g, ln_b, out);
}